// Round 2
// baseline (145.809 us; speedup 1.0000x reference)
//
#include <hip/hip_runtime.h>

#define P_TOTAL 8192
#define F_TOTAL 2048
#define TPB     256
#define TRIS    64                       // triangles per chunk (LDS-staged)
#define CHUNKS  (F_TOTAL / TRIS)         // 32
#define PBLOCKS (P_TOTAL / TPB)          // 32

// Bit-exact-vs-numpy closest-point-on-triangle. Region selected first
// (first-match priority), then TWO IEEE f32 divisions whose operands equal
// the reference's selected division operands -> results bit-identical to the
// reference's t_ab / t_ac / t_bc / v_in / w_in in every region. fp contract
// OFF so no FMA fusion (numpy does separate mul/add). Sum order (x+y)+z.
__global__ __launch_bounds__(TPB) void msdf_min_kernel(
    const float* __restrict__ verts, const int* __restrict__ faces,
    const float* __restrict__ points, unsigned long long* __restrict__ best)
{
    __shared__ float4 tri[TRIS * 3];
    const int tid = threadIdx.x;
    const int tbase = blockIdx.y * TRIS;

    if (tid < TRIS) {
        int t = tbase + tid;
        int i0 = faces[3 * t + 0], i1 = faces[3 * t + 1], i2 = faces[3 * t + 2];
        float ax = verts[3 * i0], ay = verts[3 * i0 + 1], az = verts[3 * i0 + 2];
        float bx = verts[3 * i1], by = verts[3 * i1 + 1], bz = verts[3 * i1 + 2];
        float cx = verts[3 * i2], cy = verts[3 * i2 + 1], cz = verts[3 * i2 + 2];
        tri[3 * tid + 0] = make_float4(ax, ay, az, bx);
        tri[3 * tid + 1] = make_float4(by, bz, cx, cy);
        tri[3 * tid + 2] = make_float4(cz, 0.f, 0.f, 0.f);
    }
    __syncthreads();

    const int pi = blockIdx.x * TPB + tid;
    const float px = points[3 * pi], py = points[3 * pi + 1], pz = points[3 * pi + 2];

    unsigned int best_bits = 0xFFFFFFFFu;
    int best_idx = 0;

    for (int t = 0; t < TRIS; ++t) {
        #pragma clang fp contract(off)
        float4 q0 = tri[3 * t + 0];
        float4 q1 = tri[3 * t + 1];
        float4 q2 = tri[3 * t + 2];
        float ax = q0.x, ay = q0.y, az = q0.z;
        float bx = q0.w, by = q1.x, bz = q1.y;
        float cx = q1.z, cy = q1.w, cz = q2.x;

        float abx = bx - ax, aby = by - ay, abz = bz - az;
        float acx = cx - ax, acy = cy - ay, acz = cz - az;
        float apx = px - ax, apy = py - ay, apz = pz - az;
        float d1 = (abx * apx + aby * apy) + abz * apz;
        float d2 = (acx * apx + acy * apy) + acz * apz;
        float bpx = px - bx, bpy = py - by, bpz = pz - bz;
        float d3 = (abx * bpx + aby * bpy) + abz * bpz;
        float d4 = (acx * bpx + acy * bpy) + acz * bpz;
        float cpx = px - cx, cpy = py - cy, cpz = pz - cz;
        float d5 = (abx * cpx + aby * cpy) + abz * cpz;
        float d6 = (acx * cpx + acy * cpy) + acz * cpz;

        float vc = d1 * d4 - d3 * d2;
        float vb = d5 * d2 - d1 * d6;
        float va = d3 * d6 - d5 * d4;
        float d43 = d4 - d3, d56 = d5 - d6;

        // guarded denominators, exactly as reference
        float G1 = fmaxf(d1 - d3, 1e-12f);          // t_ab denom
        float G2 = fmaxf(d2 - d6, 1e-12f);          // t_ac denom
        float G3 = fmaxf(d43 + d56, 1e-12f);        // t_bc denom
        float G4 = fmaxf((va + vb) + vc, 1e-12f);   // interior denom

        bool cA  = (d1 <= 0.f) & (d2 <= 0.f);
        bool cB  = (d3 >= 0.f) & (d4 <= d3);
        bool cAB = (vc <= 0.f) & (d1 >= 0.f) & (d3 <= 0.f);
        bool cC  = (d6 >= 0.f) & (d5 <= d6);
        bool cAC = (vb <= 0.f) & (d2 >= 0.f) & (d6 <= 0.f);
        bool cBC = (va <= 0.f) & (d43 >= 0.f) & (d56 >= 0.f);

        // first-match region id: 0=A 1=B 2=AB 3=C 4=AC 5=BC 6=interior
        int r = cA ? 0 : cB ? 1 : cAB ? 2 : cC ? 3 : cAC ? 4 : cBC ? 5 : 6;

        // Two IEEE divisions with reference-identical operands per region.
        float nv = (r == 0) ? 0.f : (r == 1) ? 1.f : (r == 2) ? d1
                 : (r == 3) ? 0.f : (r == 4) ? 0.f : (r == 5) ? d43 : vb;
        float dv = (r == 2) ? G1 : (r == 5) ? G3 : (r == 6) ? G4 : 1.f;
        float nw = (r == 3) ? 1.f : (r == 4) ? d2 : (r == 5) ? d43
                 : (r == 6) ? vc : 0.f;
        float dw = (r == 4) ? G2 : (r == 5) ? G3 : (r == 6) ? G4 : 1.f;

        float qv = nv / dv;                 // == t_ab / t_bc / v_in / const
        float bw = nw / dw;                 // == t_ac / t_bc / w_in / const
        float bv = (r == 5) ? (1.0f - qv) : qv;   // reference: 1.0 - t_bc
        float bu = (1.0f - bv) - bw;

        // reference: cp = a*bu + b*bv + c*bw; dist2 = sum((p-cp)^2)
        float cpx2 = (ax * bu + bx * bv) + cx * bw;
        float cpy2 = (ay * bu + by * bv) + cy * bw;
        float cpz2 = (az * bu + bz * bv) + cz * bw;
        float dx = px - cpx2, dy = py - cpy2, dz = pz - cpz2;
        float dist2 = (dx * dx + dy * dy) + dz * dz;

        unsigned int bits = __float_as_uint(dist2);   // dist2 >= 0: order-preserving
        if (bits < best_bits) { best_bits = bits; best_idx = tbase + t; }
    }

    unsigned long long key =
        ((unsigned long long)best_bits << 32) | (unsigned int)best_idx;
    atomicMin(&best[pi], key);
}

// Unpack per-point min, write dist + assoc (as float; whole out buffer is
// read as f32), block-reduce loss into out[0].
__global__ __launch_bounds__(256) void msdf_finalize(
    const unsigned long long* __restrict__ best, float* __restrict__ out)
{
    __shared__ float wsum[4];
    int i = blockIdx.x * 256 + threadIdx.x;
    unsigned long long key = best[i];
    float dist = __uint_as_float((unsigned int)(key >> 32));
    unsigned int idx = (unsigned int)(key & 0xFFFFFFFFu);
    out[1 + i] = dist;
    out[1 + P_TOTAL + i] = (float)idx;

    float s = dist;
    #pragma unroll
    for (int off = 32; off > 0; off >>= 1) s += __shfl_down(s, off, 64);
    int lane = threadIdx.x & 63, wid = threadIdx.x >> 6;
    if (lane == 0) wsum[wid] = s;
    __syncthreads();
    if (threadIdx.x == 0) {
        float tot = wsum[0] + wsum[1] + wsum[2] + wsum[3];
        atomicAdd(out, tot * (1000.0f / (float)P_TOTAL));
    }
}

extern "C" void kernel_launch(void* const* d_in, const int* in_sizes, int n_in,
                              void* d_out, int out_size, void* d_ws, size_t ws_size,
                              hipStream_t stream) {
    const float* verts  = (const float*)d_in[0];
    const int*   faces  = (const int*)d_in[1];
    const float* points = (const float*)d_in[2];
    float* out = (float*)d_out;
    unsigned long long* best = (unsigned long long*)d_ws;

    // init packed mins to +inf-equivalent, zero the loss accumulator
    hipMemsetAsync(best, 0xFF, P_TOTAL * sizeof(unsigned long long), stream);
    hipMemsetAsync(d_out, 0, sizeof(float), stream);

    dim3 grid(PBLOCKS, CHUNKS);
    msdf_min_kernel<<<grid, dim3(TPB), 0, stream>>>(verts, faces, points, best);
    msdf_finalize<<<dim3(P_TOTAL / 256), dim3(256), 0, stream>>>(best, out);
}

// Round 3
// 133.735 us; speedup vs baseline: 1.0903x; 1.0903x over previous
//
#include <hip/hip_runtime.h>

#define P_TOTAL 8192
#define F_TOTAL 2048
#define TPB     256
#define TRIS    32                       // triangles per chunk (LDS-staged)
#define CHUNKS  (F_TOTAL / TRIS)         // 64 -> 2048 blocks = 8/CU = 100% static occ
#define PBLOCKS (P_TOTAL / TPB)          // 32

// Bit-exact-vs-numpy closest-point-on-triangle. Region selected first
// (first-match priority), then TWO IEEE f32 divisions whose operands equal
// the reference's selected division operands -> results bit-identical to the
// reference's t_ab / t_ac / t_bc / v_in / w_in in every region. fp contract
// OFF so no FMA fusion (numpy does separate mul/add). Sum order (x+y)+z.
__global__ __launch_bounds__(TPB) void msdf_min_kernel(
    const float* __restrict__ verts, const int* __restrict__ faces,
    const float* __restrict__ points, unsigned long long* __restrict__ best,
    float* __restrict__ out)
{
    __shared__ float4 tri[TRIS * 3];
    const int tid = threadIdx.x;
    const int tbase = blockIdx.y * TRIS;

    // zero the loss accumulator exactly once per launch (stream order puts
    // all min_kernel blocks before finalize's atomicAdd)
    if (blockIdx.x == 0 && blockIdx.y == 0 && tid == 0) out[0] = 0.0f;

    if (tid < TRIS) {
        int t = tbase + tid;
        int i0 = faces[3 * t + 0], i1 = faces[3 * t + 1], i2 = faces[3 * t + 2];
        float ax = verts[3 * i0], ay = verts[3 * i0 + 1], az = verts[3 * i0 + 2];
        float bx = verts[3 * i1], by = verts[3 * i1 + 1], bz = verts[3 * i1 + 2];
        float cx = verts[3 * i2], cy = verts[3 * i2 + 1], cz = verts[3 * i2 + 2];
        tri[3 * tid + 0] = make_float4(ax, ay, az, bx);
        tri[3 * tid + 1] = make_float4(by, bz, cx, cy);
        tri[3 * tid + 2] = make_float4(cz, 0.f, 0.f, 0.f);
    }
    __syncthreads();

    const int pi = blockIdx.x * TPB + tid;
    const float px = points[3 * pi], py = points[3 * pi + 1], pz = points[3 * pi + 2];

    unsigned int best_bits = 0xFFFFFFFFu;
    int best_idx = 0;

    #pragma unroll 2
    for (int t = 0; t < TRIS; ++t) {
        #pragma clang fp contract(off)
        float4 q0 = tri[3 * t + 0];
        float4 q1 = tri[3 * t + 1];
        float4 q2 = tri[3 * t + 2];
        float ax = q0.x, ay = q0.y, az = q0.z;
        float bx = q0.w, by = q1.x, bz = q1.y;
        float cx = q1.z, cy = q1.w, cz = q2.x;

        float abx = bx - ax, aby = by - ay, abz = bz - az;
        float acx = cx - ax, acy = cy - ay, acz = cz - az;
        float apx = px - ax, apy = py - ay, apz = pz - az;
        float d1 = (abx * apx + aby * apy) + abz * apz;
        float d2 = (acx * apx + acy * apy) + acz * apz;
        float bpx = px - bx, bpy = py - by, bpz = pz - bz;
        float d3 = (abx * bpx + aby * bpy) + abz * bpz;
        float d4 = (acx * bpx + acy * bpy) + acz * bpz;
        float cpx = px - cx, cpy = py - cy, cpz = pz - cz;
        float d5 = (abx * cpx + aby * cpy) + abz * cpz;
        float d6 = (acx * cpx + acy * cpy) + acz * cpz;

        float vc = d1 * d4 - d3 * d2;
        float vb = d5 * d2 - d1 * d6;
        float va = d3 * d6 - d5 * d4;
        float d43 = d4 - d3, d56 = d5 - d6;

        // guarded denominators, exactly as reference
        float G1 = fmaxf(d1 - d3, 1e-12f);          // t_ab denom
        float G2 = fmaxf(d2 - d6, 1e-12f);          // t_ac denom
        float G3 = fmaxf(d43 + d56, 1e-12f);        // t_bc denom
        float G4 = fmaxf((va + vb) + vc, 1e-12f);   // interior denom

        bool cA  = (d1 <= 0.f) & (d2 <= 0.f);
        bool cB  = (d3 >= 0.f) & (d4 <= d3);
        bool cAB = (vc <= 0.f) & (d1 >= 0.f) & (d3 <= 0.f);
        bool cC  = (d6 >= 0.f) & (d5 <= d6);
        bool cAC = (vb <= 0.f) & (d2 >= 0.f) & (d6 <= 0.f);
        bool cBC = (va <= 0.f) & (d43 >= 0.f) & (d56 >= 0.f);

        // first-match region id: 0=A 1=B 2=AB 3=C 4=AC 5=BC 6=interior
        int r = cA ? 0 : cB ? 1 : cAB ? 2 : cC ? 3 : cAC ? 4 : cBC ? 5 : 6;

        // Two IEEE divisions with reference-identical operands per region.
        float nv = (r == 0) ? 0.f : (r == 1) ? 1.f : (r == 2) ? d1
                 : (r == 3) ? 0.f : (r == 4) ? 0.f : (r == 5) ? d43 : vb;
        float dv = (r == 2) ? G1 : (r == 5) ? G3 : (r == 6) ? G4 : 1.f;
        float nw = (r == 3) ? 1.f : (r == 4) ? d2 : (r == 5) ? d43
                 : (r == 6) ? vc : 0.f;
        float dw = (r == 4) ? G2 : (r == 5) ? G3 : (r == 6) ? G4 : 1.f;

        float qv = nv / dv;                 // == t_ab / t_bc / v_in / const
        float bw = nw / dw;                 // == t_ac / t_bc / w_in / const
        float bv = (r == 5) ? (1.0f - qv) : qv;   // reference: 1.0 - t_bc
        float bu = (1.0f - bv) - bw;

        // reference: cp = a*bu + b*bv + c*bw; dist2 = sum((p-cp)^2)
        float cpx2 = (ax * bu + bx * bv) + cx * bw;
        float cpy2 = (ay * bu + by * bv) + cy * bw;
        float cpz2 = (az * bu + bz * bv) + cz * bw;
        float dx = px - cpx2, dy = py - cpy2, dz = pz - cpz2;
        float dist2 = (dx * dx + dy * dy) + dz * dz;

        unsigned int bits = __float_as_uint(dist2);   // dist2 >= 0: order-preserving
        if (bits < best_bits) { best_bits = bits; best_idx = tbase + t; }
    }

    unsigned long long key =
        ((unsigned long long)best_bits << 32) | (unsigned int)best_idx;
    atomicMin(&best[pi], key);
}

// Unpack per-point min, write dist + assoc (as float; whole out buffer is
// read as f32), block-reduce loss into out[0].
__global__ __launch_bounds__(256) void msdf_finalize(
    const unsigned long long* __restrict__ best, float* __restrict__ out)
{
    __shared__ float wsum[4];
    int i = blockIdx.x * 256 + threadIdx.x;
    unsigned long long key = best[i];
    float dist = __uint_as_float((unsigned int)(key >> 32));
    unsigned int idx = (unsigned int)(key & 0xFFFFFFFFu);
    out[1 + i] = dist;
    out[1 + P_TOTAL + i] = (float)idx;

    float s = dist;
    #pragma unroll
    for (int off = 32; off > 0; off >>= 1) s += __shfl_down(s, off, 64);
    int lane = threadIdx.x & 63, wid = threadIdx.x >> 6;
    if (lane == 0) wsum[wid] = s;
    __syncthreads();
    if (threadIdx.x == 0) {
        float tot = wsum[0] + wsum[1] + wsum[2] + wsum[3];
        atomicAdd(out, tot * (1000.0f / (float)P_TOTAL));
    }
}

extern "C" void kernel_launch(void* const* d_in, const int* in_sizes, int n_in,
                              void* d_out, int out_size, void* d_ws, size_t ws_size,
                              hipStream_t stream) {
    const float* verts  = (const float*)d_in[0];
    const int*   faces  = (const int*)d_in[1];
    const float* points = (const float*)d_in[2];
    float* out = (float*)d_out;
    unsigned long long* best = (unsigned long long*)d_ws;

    // init packed mins to +inf-equivalent (can't rely on 0xAA poison for the
    // validation call, so keep this one memset)
    hipMemsetAsync(best, 0xFF, P_TOTAL * sizeof(unsigned long long), stream);

    dim3 grid(PBLOCKS, CHUNKS);
    msdf_min_kernel<<<grid, dim3(TPB), 0, stream>>>(verts, faces, points, best, out);
    msdf_finalize<<<dim3(P_TOTAL / 256), dim3(256), 0, stream>>>(best, out);
}

// Round 4
// 121.008 us; speedup vs baseline: 1.2050x; 1.1052x over previous
//
#include <hip/hip_runtime.h>

#define P_TOTAL 8192
#define F_TOTAL 2048
#define TPB     256                      // 4 waves; wave w owns point base+w
#define CHUNK   256                      // tris staged per LDS pass (12 KB)
#define NCHUNK  (F_TOTAL / CHUNK)        // 8
#define SUBS    (CHUNK / 64)             // 4 tris per lane per chunk

// Wave-per-point exact scan. Lane l of wave w evaluates tris {s*64+l} of each
// chunk for point (blockIdx.x*4 + w). Bit-exact-vs-numpy arithmetic (contract
// off, numpy op order, region-first + IEEE divisions with reference-identical
// operands; shared denominator D is bit-safe: vertex regions divide by 1.0,
// and 0/G == +0 matches the reference's 0). Packed (bits<<32|idx) shuffle-min
// reproduces argmin first-match semantics. No ws, no atomics, no memset.
__global__ __launch_bounds__(TPB) void msdf_main(
    const float* __restrict__ verts, const int* __restrict__ faces,
    const float* __restrict__ points, float* __restrict__ out)
{
    __shared__ float4 tri[CHUNK * 3];    // 12 KB
    const int tid  = threadIdx.x;
    const int lane = tid & 63;
    const int w    = tid >> 6;
    const int p    = blockIdx.x * 4 + w;          // wave-uniform point id

    const float px = points[3 * p], py = points[3 * p + 1], pz = points[3 * p + 2];

    unsigned int best_bits = 0xFFFFFFFFu;
    int best_idx = 0;

    for (int c = 0; c < NCHUNK; ++c) {
        __syncthreads();                 // protect LDS buffer reuse
        {   // stage: thread tid gathers tri c*256+tid (1:1)
            int tg = c * CHUNK + tid;
            int i0 = faces[3 * tg + 0], i1 = faces[3 * tg + 1], i2 = faces[3 * tg + 2];
            float ax = verts[3 * i0], ay = verts[3 * i0 + 1], az = verts[3 * i0 + 2];
            float bx = verts[3 * i1], by = verts[3 * i1 + 1], bz = verts[3 * i1 + 2];
            float cx = verts[3 * i2], cy = verts[3 * i2 + 1], cz = verts[3 * i2 + 2];
            tri[3 * tid + 0] = make_float4(ax, ay, az, bx);
            tri[3 * tid + 1] = make_float4(by, bz, cx, cy);
            tri[3 * tid + 2] = make_float4(cz, 0.f, 0.f, 0.f);
        }
        __syncthreads();

        #pragma unroll
        for (int s = 0; s < SUBS; ++s) {
            #pragma clang fp contract(off)
            int tl = s * 64 + lane;
            float4 q0 = tri[3 * tl + 0];
            float4 q1 = tri[3 * tl + 1];
            float4 q2 = tri[3 * tl + 2];
            float ax = q0.x, ay = q0.y, az = q0.z;
            float bx = q0.w, by = q1.x, bz = q1.y;
            float cx = q1.z, cy = q1.w, cz = q2.x;

            float abx = bx - ax, aby = by - ay, abz = bz - az;
            float acx = cx - ax, acy = cy - ay, acz = cz - az;
            float apx = px - ax, apy = py - ay, apz = pz - az;
            float d1 = (abx * apx + aby * apy) + abz * apz;
            float d2 = (acx * apx + acy * apy) + acz * apz;
            float bpx = px - bx, bpy = py - by, bpz = pz - bz;
            float d3 = (abx * bpx + aby * bpy) + abz * bpz;
            float d4 = (acx * bpx + acy * bpy) + acz * bpz;
            float cpx = px - cx, cpy = py - cy, cpz = pz - cz;
            float d5 = (abx * cpx + aby * cpy) + abz * cpz;
            float d6 = (acx * cpx + acy * cpy) + acz * cpz;

            float vc = d1 * d4 - d3 * d2;
            float vb = d5 * d2 - d1 * d6;
            float va = d3 * d6 - d5 * d4;
            float d43 = d4 - d3, d56 = d5 - d6;

            float G1 = fmaxf(d1 - d3, 1e-12f);          // t_ab denom
            float G2 = fmaxf(d2 - d6, 1e-12f);          // t_ac denom
            float G3 = fmaxf(d43 + d56, 1e-12f);        // t_bc denom
            float G4 = fmaxf((va + vb) + vc, 1e-12f);   // interior denom

            bool cA  = (d1 <= 0.f) & (d2 <= 0.f);
            bool cB  = (d3 >= 0.f) & (d4 <= d3);
            bool cAB = (vc <= 0.f) & (d1 >= 0.f) & (d3 <= 0.f);
            bool cC  = (d6 >= 0.f) & (d5 <= d6);
            bool cAC = (vb <= 0.f) & (d2 >= 0.f) & (d6 <= 0.f);
            bool cBC = (va <= 0.f) & (d43 >= 0.f) & (d56 >= 0.f);

            // first-match selects; single shared denominator D (bit-safe).
            float nv = cA ? 0.f : cB ? 1.f : cAB ? d1 : cC ? 0.f
                     : cAC ? 0.f : cBC ? d43 : vb;
            float nw = cA ? 0.f : cB ? 0.f : cAB ? 0.f : cC ? 1.f
                     : cAC ? d2 : cBC ? d43 : vc;
            float D  = cA ? 1.f : cB ? 1.f : cAB ? G1 : cC ? 1.f
                     : cAC ? G2 : cBC ? G3 : G4;
            // first-match == BC (mask-only ops, SALU)
            bool fBC = cBC && !(cA || cB || cAB || cC || cAC);

            float qv = nv / D;                    // IEEE, ref-identical operands
            float bw = nw / D;
            float bv = fBC ? (1.0f - qv) : qv;    // reference: 1.0 - t_bc
            float bu = (1.0f - bv) - bw;

            float cpx2 = (ax * bu + bx * bv) + cx * bw;
            float cpy2 = (ay * bu + by * bv) + cy * bw;
            float cpz2 = (az * bu + bz * bv) + cz * bw;
            float dx = px - cpx2, dy = py - cpy2, dz = pz - cpz2;
            float dist2 = (dx * dx + dy * dy) + dz * dz;

            unsigned int bits = __float_as_uint(dist2);   // >=0: order-preserving
            if (bits < best_bits) { best_bits = bits; best_idx = c * CHUNK + tl; }
        }
    }

    // in-wave packed min: smallest (bits, idx) == first-match argmin
    unsigned long long key =
        ((unsigned long long)best_bits << 32) | (unsigned int)best_idx;
    #pragma unroll
    for (int off = 32; off > 0; off >>= 1) {
        unsigned int hi = (unsigned int)(key >> 32);
        unsigned int lo = (unsigned int)(key & 0xFFFFFFFFu);
        unsigned int ohi = __shfl_down(hi, off, 64);
        unsigned int olo = __shfl_down(lo, off, 64);
        unsigned long long ok = ((unsigned long long)ohi << 32) | olo;
        key = (ok < key) ? ok : key;
    }
    if (lane == 0) {
        out[1 + p]           = __uint_as_float((unsigned int)(key >> 32));
        out[1 + P_TOTAL + p] = (float)(unsigned int)(key & 0xFFFFFFFFu);
    }
}

// Deterministic single-block loss reduction: out[0] = sum(dist) * 1000/P.
__global__ __launch_bounds__(256) void msdf_loss(float* __restrict__ out)
{
    __shared__ float wsum[4];
    float s = 0.f;
    for (int k = 0; k < P_TOTAL / 256; ++k)
        s += out[1 + k * 256 + threadIdx.x];
    #pragma unroll
    for (int off = 32; off > 0; off >>= 1) s += __shfl_down(s, off, 64);
    int lane = threadIdx.x & 63, w = threadIdx.x >> 6;
    if (lane == 0) wsum[w] = s;
    __syncthreads();
    if (threadIdx.x == 0) {
        float tot = ((wsum[0] + wsum[1]) + wsum[2]) + wsum[3];
        out[0] = tot * (1000.0f / (float)P_TOTAL);
    }
}

extern "C" void kernel_launch(void* const* d_in, const int* in_sizes, int n_in,
                              void* d_out, int out_size, void* d_ws, size_t ws_size,
                              hipStream_t stream) {
    const float* verts  = (const float*)d_in[0];
    const int*   faces  = (const int*)d_in[1];
    const float* points = (const float*)d_in[2];
    float* out = (float*)d_out;

    msdf_main<<<dim3(P_TOTAL / 4), dim3(TPB), 0, stream>>>(verts, faces, points, out);
    msdf_loss<<<dim3(1), dim3(256), 0, stream>>>(out);
}